// Round 2
// 262.566 us; speedup vs baseline: 1.0027x; 1.0027x over previous
//
#include <hip/hip_runtime.h>

// Problem constants (match reference)
#define BATCH 32
#define T_IN 1024
#define TP 1025      // T+1 (phoneme + silence token)
#define EMB 384
#define GROUPS 4
#define GC 96        // channels per group
#define KDIM 288     // GC * 3 taps (im2col K), 9 ksteps of 32

typedef __attribute__((ext_vector_type(8))) short short8;   // 8 bf16 (4 VGPRs)
typedef __attribute__((ext_vector_type(4))) float f32x4;    // 4 fp32 (native vec; ok for nontemporal builtin)

#define N_WPACK (GROUPS * 9 * 6 * 64 * 8)   // 110592 bf16 elements
#define PREP_BLOCKS ((N_WPACK + 255) / 256) // 432
#define CONV_BLOCKS (17 * GROUPS * BATCH)   // 2176

__device__ __forceinline__ unsigned short f2bf(float f) {
    union { float f; unsigned u; } v; v.f = f;
    unsigned u = v.u + 0x7fffu + ((v.u >> 16) & 1u);  // RNE
    return (unsigned short)(u >> 16);
}

// ---------------------------------------------------------------------------
// Kernel A (setup): blocks [0, PREP_BLOCKS) pack w1 -> bf16 MFMA B-fragment
// layout + init pred to b2; blocks [PREP_BLOCKS, PREP_BLOCKS+BATCH) do the
// per-batch inclusive cumsum with all 17 loads issued up front (the only
// serial dependence left is the cheap shfl-scan offset chain).
// ---------------------------------------------------------------------------
__global__ __launch_bounds__(256) void setup_kernel(const float* __restrict__ w1,
                                                    const float* __restrict__ b2,
                                                    const int* __restrict__ dur,
                                                    unsigned short* __restrict__ wpack,
                                                    float* __restrict__ pred,
                                                    int* __restrict__ cum) {
    const int bid = blockIdx.x;
    if (bid < PREP_BLOCKS) {
        // --- weight pack + pred init (identical math to previous prep) ---
        int i = bid * 256 + threadIdx.x;
        if (i < N_WPACK) {
            int j = i & 7;
            int lane = (i >> 3) & 63;
            int rest = i >> 9;
            int nt = rest % 6; rest /= 6;
            int ks = rest % 9;
            int g = rest / 9;
            int oc = nt * 16 + (lane & 15);
            int kk = ks * 32 + (lane >> 4) * 8 + j;
            int k = kk / 96, ic = kk % 96;
            float v = w1[((size_t)(g * GC + oc) * GC + ic) * 3 + k];
            wpack[i] = f2bf(v);
        }
        if (i < BATCH * TP) pred[i] = b2[0];
    } else {
        // --- scan: one wave per batch, loads batched ahead of the chain ---
        const int b = bid - PREP_BLOCKS;
        const int l = threadIdx.x;
        if (l >= 64) return;
        const int* d = dur + b * TP;
        int* c = cum + b * TP;
        int v[17];
#pragma unroll
        for (int r = 0; r < 17; ++r) {
            int idx = r * 64 + l;
            v[r] = (idx < TP) ? d[idx] : 0;   // 17 independent loads in flight
        }
        int offset = 0;
#pragma unroll
        for (int r = 0; r < 17; ++r) {
            int s = v[r];
#pragma unroll
            for (int off = 1; off < 64; off <<= 1) {
                int n = __shfl_up(s, off, 64);
                if (l >= off) s += n;
            }
            int idx = r * 64 + l;
            if (idx < TP) c[idx] = s + offset;
            offset += __shfl(s, 63, 64);
        }
    }
}

// ---------------------------------------------------------------------------
// Kernel B (main): conv blocks and gather blocks round-robin interleaved so
// the MFMA-heavy conv work and the HBM-write-heavy gather work co-reside on
// every CU. Uniform per-block branch (no divergence).
//
// conv sub-block: grouped conv (k=3,pad 1) + ReLU + 1x1 conv via bf16 MFMA.
//   sub -> (tile 17, g 4, b 32); 4 waves x 16 rows x 96 oc; per kstep:
//   1 ds_read_b128 A-frag + 6 global 16B B-frags + 6 MFMAs.
// gather sub-block: 64 frames x 96 float4 length-regulate gather with
//   nontemporal streaming stores (output is never re-read).
// ---------------------------------------------------------------------------
__global__ __launch_bounds__(256) void main_kernel(const float* __restrict__ phoneme,
                                                   const float* __restrict__ silence,
                                                   const float* __restrict__ b1,
                                                   const float* __restrict__ w2,
                                                   const unsigned short* __restrict__ wpack,
                                                   const int* __restrict__ cum,
                                                   float* __restrict__ pred,
                                                   float* __restrict__ out,
                                                   int t_out, int nfb, int n_gather) {
    __shared__ __align__(16) unsigned short xs[66][104];  // conv x-tile, bf16
    __shared__ float red[4][16][17];                      // conv reduction
    __shared__ int sidx[64];                              // gather frame->token
    __shared__ int stotal;

    const int bid = blockIdx.x;
    const int nc = CONV_BLOCKS;
    const int ng = n_gather;
    const int mn = nc < ng ? nc : ng;
    bool isConv;
    int sub;
    if (bid < 2 * mn) {
        isConv = (bid & 1);
        sub = bid >> 1;
    } else {
        isConv = (nc > ng);
        sub = mn + (bid - 2 * mn);
    }

    const int tid = threadIdx.x;

    if (isConv) {
        // ------------------- conv path -------------------
        const int tile = sub % 17;
        const int g = (sub / 17) & 3;
        const int b = sub / (17 * 4);
        const int t0 = tile * 64;

        // Stage x-tile (fp32 -> bf16): 66 rows x 96 ch of ph[b, :, g*96..]
        for (int e = tid; e < 66 * 24; e += 256) {
            int row = e / 24;
            int v = e - row * 24;
            int r = t0 - 1 + row;
            f32x4 val;
            if (r < 0 || r > T_IN) {
                val = (f32x4){0.f, 0.f, 0.f, 0.f};
            } else if (r == T_IN) {
                val = *(const f32x4*)(silence + g * GC + v * 4);
            } else {
                val = *(const f32x4*)(phoneme + ((size_t)(b * T_IN + r)) * EMB + g * GC + v * 4);
            }
            ushort4 pk;
            pk.x = f2bf(val.x); pk.y = f2bf(val.y); pk.z = f2bf(val.z); pk.w = f2bf(val.w);
            *(ushort4*)&xs[row][v * 4] = pk;
        }
        __syncthreads();

        const int w = tid >> 6;
        const int lane = tid & 63;
        const int quad = lane >> 4;
        const int lr = lane & 15;

        f32x4 acc[6];
#pragma unroll
        for (int nt = 0; nt < 6; ++nt) acc[nt] = (f32x4){0.f, 0.f, 0.f, 0.f};

        const unsigned short* wg = wpack + (size_t)g * 9 * 6 * 512;

#pragma unroll
        for (int ks = 0; ks < 9; ++ks) {
            const int k = ks / 3;                       // tap index (kstep-uniform)
            const int icoff = 32 * (ks % 3) + quad * 8; // ic offset within group
            const int lrow = w * 16 + lr + k;           // LDS row (t0-1 origin)
            short8 a = *(const short8*)&xs[lrow][icoff];
#pragma unroll
            for (int nt = 0; nt < 6; ++nt) {
                short8 bf = *(const short8*)(wg + ((size_t)(ks * 6 + nt) * 64 + lane) * 8);
                acc[nt] = __builtin_amdgcn_mfma_f32_16x16x32_bf16(a, bf, acc[nt], 0, 0, 0);
            }
        }

        // Epilogue: bias + ReLU + w2-weighted partial sum over this lane's oc
        // D layout: row(m) = quad*4+reg, col(oc) = lane&15  [m89/m91 verified]
        float s[4] = {0.f, 0.f, 0.f, 0.f};
#pragma unroll
        for (int nt = 0; nt < 6; ++nt) {
            int oc = g * GC + nt * 16 + lr;
            float bias = b1[oc];
            float wc = w2[oc];
#pragma unroll
            for (int reg = 0; reg < 4; ++reg) {
                float h = acc[nt][reg] + bias;
                h = h > 0.f ? h : 0.f;
                s[reg] += wc * h;
            }
        }
#pragma unroll
        for (int reg = 0; reg < 4; ++reg) red[w][quad * 4 + reg][lr] = s[reg];
        __syncthreads();

        if (tid < 64) {
            int wv = tid >> 4, m = tid & 15;
            float sum = 0.f;
#pragma unroll
            for (int c2 = 0; c2 < 16; ++c2) sum += red[wv][m][c2];
            int t = t0 + wv * 16 + m;
            if (t < TP) atomicAdd(pred + b * TP + t, sum);
        }
    } else {
        // ------------------- gather path -------------------
        const int b = sub / nfb;
        const int f0 = (sub - b * nfb) * 64;

        if (tid == 0) stotal = cum[b * TP + T_IN];
        if (tid < 64) {
            int t = f0 + tid;
            int id = 0;
            if (t < t_out) {
                const int* c = cum + b * TP;
                int lo = 0, hi = TP;
                while (lo < hi) {
                    int mid = (lo + hi) >> 1;
                    if (c[mid] <= t) lo = mid + 1; else hi = mid;
                }
                id = lo > T_IN ? T_IN : lo;
            }
            sidx[tid] = id;
        }
        __syncthreads();

        const int total = stotal;
        const f32x4* ph4 = (const f32x4*)phoneme;
        const f32x4* s4 = (const f32x4*)silence;
        f32x4* out4 = (f32x4*)out;

        for (int e = tid; e < 64 * 96; e += 256) {
            int fl = e / 96;
            int v = e - fl * 96;
            int t = f0 + fl;
            if (t >= t_out) continue;
            f32x4 val;
            if (t >= total) {
                val = (f32x4){0.f, 0.f, 0.f, 0.f};
            } else {
                int id = sidx[fl];
                val = (id == T_IN) ? s4[v] : ph4[((size_t)(b * T_IN) + id) * 96 + v];
            }
            __builtin_nontemporal_store(val, &out4[((size_t)b * t_out + t) * 96 + v]);
        }
    }
}

// ---------------------------------------------------------------------------
extern "C" void kernel_launch(void* const* d_in, const int* in_sizes, int n_in,
                              void* d_out, int out_size, void* d_ws, size_t ws_size,
                              hipStream_t stream) {
    const float* phoneme = (const float*)d_in[0];
    const float* silence = (const float*)d_in[1];
    const float* conv1_w = (const float*)d_in[2];
    const float* conv1_b = (const float*)d_in[3];
    const float* conv2_w = (const float*)d_in[4];
    const float* conv2_b = (const float*)d_in[5];
    const int* durations = (const int*)d_in[6];
    // d_in[7] = t_out on device; derive from out_size host-side instead.
    const int t_out = (out_size - BATCH * TP) / (BATCH * EMB);

    float* out_expanded = (float*)d_out;                            // [B, t_out, EMB]
    float* out_pred = (float*)d_out + (size_t)BATCH * t_out * EMB;  // [B, TP]

    int* cum = (int*)d_ws;                                          // 131200 B
    unsigned short* wpack = (unsigned short*)((char*)d_ws + 131200); // 221184 B, 16B-aligned

    const int nfb = (t_out + 63) / 64;
    const int n_gather = nfb * BATCH;

    setup_kernel<<<PREP_BLOCKS + BATCH, 256, 0, stream>>>(
        conv1_w, conv2_b, durations, wpack, out_pred, cum);
    main_kernel<<<CONV_BLOCKS + n_gather, 256, 0, stream>>>(
        phoneme, silence, conv1_b, conv2_w, wpack, cum, out_pred, out_expanded,
        t_out, nfb, n_gather);
}